// Round 5
// baseline (209.464 us; speedup 1.0000x reference)
//
#include <hip/hip_runtime.h>

#define HW 1659      // 21*79
#define PADID 4096
#define EMB 20
#define HID 32
#define MAXLEN 64
#define SPB 4        // samples per block

// One fused kernel: presence -> bag -> emb (to LDS + global) -> packed RNN.
// 4 samples/block, 128 threads. Wave w owns samples {2w, 2w+1}.
__global__ __launch_bounds__(128, 4) void fused_kernel(
    const int* __restrict__ chars, const int* __restrict__ colors,
    const float* __restrict__ emb_table,
    const float* __restrict__ W_ih, const float* __restrict__ W_hh,
    const float* __restrict__ b_ih, const float* __restrict__ b_hh,
    float* __restrict__ out_h, float* __restrict__ out_emb,
    float* __restrict__ out_bag)
{
    // pres (16 KB) and xbuf (20 KB) live in the same LDS region (phases disjoint)
    __shared__ __align__(16) unsigned char smem_raw[SPB * MAXLEN * EMB * 4];
    unsigned char (*pres)[4096]      = (unsigned char (*)[4096])smem_raw;
    float (*xbuf)[MAXLEN][EMB]       = (float (*)[MAXLEN][EMB])smem_raw;
    __shared__ int bagl[SPB][64];
    __shared__ float hbuf[SPB][HID];

    const int tid   = threadIdx.x;
    const int lane  = tid & 63;
    const int wv    = tid >> 6;          // wave 0/1
    const int gbase = blockIdx.x * SPB;

    // init bagl (256 ints) + zero pres (1024 uint4)
    ((int*)bagl)[tid]       = PADID;
    ((int*)bagl)[tid + 128] = PADID;
    {
        uint4* p4 = (uint4*)smem_raw;
#pragma unroll
        for (int i = 0; i < 8; i++) p4[tid + 128 * i] = make_uint4(0u, 0u, 0u, 0u);
    }
    __syncthreads();

    // ---- presence fill: pres[s][g]=1 (idempotent byte stores, int4 loads) ----
    for (int s = 0; s < SPB; s++) {
        const int base = (gbase + s) * HW;
        unsigned char* pr = pres[s];
        const int pe = (4 - (base & 3)) & 3;       // peel to 16B alignment
        if (tid < pe) {
            int g = (chars[base + tid] << 4) + colors[base + tid];
            pr[g] = 1;
        }
        const int nv = (HW - pe) >> 2;
        const int nt = HW - pe - (nv << 2);
        const int4* c4 = (const int4*)(chars + base + pe);
        const int4* k4 = (const int4*)(colors + base + pe);
        for (int v = tid; v < nv; v += 128) {
            int4 c = c4[v], k = k4[v];
            pr[(c.x << 4) + k.x] = 1;
            pr[(c.y << 4) + k.y] = 1;
            pr[(c.z << 4) + k.z] = 1;
            pr[(c.w << 4) + k.w] = 1;
        }
        if (tid < nt) {
            int i = base + pe + (nv << 2) + tid;
            pr[(chars[i] << 4) + colors[i]] = 1;
        }
    }
    __syncthreads();

    // ---- scan + extract: wave wv does samples 2wv, 2wv+1; lane owns 64 ids ----
    for (int si = 0; si < 2; si++) {
        const int s = 2 * wv + si;
        const uint4* p4 = (const uint4*)pres[s];   // 256 uint4
        uint4 a = p4[4 * lane + 0], b2 = p4[4 * lane + 1];
        uint4 c = p4[4 * lane + 2], d  = p4[4 * lane + 3];
        const unsigned M = 0x01010101u;
        int cnt = __popc(a.x & M) + __popc(a.y & M) + __popc(a.z & M) + __popc(a.w & M)
                + __popc(b2.x & M) + __popc(b2.y & M) + __popc(b2.z & M) + __popc(b2.w & M)
                + __popc(c.x & M) + __popc(c.y & M) + __popc(c.z & M) + __popc(c.w & M)
                + __popc(d.x & M) + __popc(d.y & M) + __popc(d.z & M) + __popc(d.w & M);
        int pre = cnt;
#pragma unroll
        for (int dd = 1; dd < 64; dd <<= 1) {
            int v = __shfl_up(pre, dd, 64);
            if (lane >= dd) pre += v;
        }
        int p = pre - cnt;                          // exclusive prefix
        unsigned wrd[16] = {a.x, a.y, a.z, a.w, b2.x, b2.y, b2.z, b2.w,
                            c.x, c.y, c.z, c.w, d.x, d.y, d.z, d.w};
#pragma unroll
        for (int wi = 0; wi < 16; wi++) {
#pragma unroll
            for (int k = 0; k < 4; k++) {
                if ((wrd[wi] >> (8 * k)) & 1) {
                    if (p < 64) bagl[s][p] = 64 * lane + 4 * wi + k;
                    p++;
                }
            }
        }
    }
    __syncthreads();    // all pres reads done (xbuf may now overwrite), bagl final

    // ---- bag output (256 entries) ----
    out_bag[(size_t)gbase * 64 + tid]       = (float)((int*)bagl)[tid];
    out_bag[(size_t)gbase * 64 + 128 + tid] = (float)((int*)bagl)[tid + 128];

    // ---- gather: 4*64*5 float4 -> LDS xbuf + global out_emb ----
    const float4* tab4 = (const float4*)emb_table;
    float4* dstb = (float4*)(out_emb + (size_t)gbase * (MAXLEN * EMB));
    for (int q = tid; q < SPB * MAXLEN * 5; q += 128) {
        int s = q / 320;
        int r = q - 320 * s;
        int t = r / 5;
        int m = r - 5 * t;
        int row = bagl[s][t];                      // row 4096 is the zero row
        float4 val = tab4[row * 5 + m];
        dstb[q] = val;
        ((float4*)&xbuf[s][t][0])[m] = val;        // offset s*5120+t*80+m*16: aligned
    }
    __syncthreads();

    // ---- packed RNN: thread=(sample slot, hidden); h wave-private ----
    const int ib = tid >> 5;          // 0..3 (wave 0: 0,1; wave 1: 2,3)
    const int j  = tid & 31;

    float wih[EMB];
#pragma unroll
    for (int k = 0; k < EMB; k++) wih[k] = W_ih[j * EMB + k];
    float whh[HID];
#pragma unroll
    for (int k = 0; k < HID; k++) whh[k] = W_hh[j * HID + k];
    // volatile pin: cannot be sunk/duplicated -> loads execute once, values stay
#pragma unroll
    for (int k = 0; k < EMB; k++) asm volatile("" : "+v"(wih[k]));
#pragma unroll
    for (int k = 0; k < HID; k++) asm volatile("" : "+v"(whh[k]));
    const float sbias = b_ih[j] + b_hh[j];

    // length via one ballot over LDS bagl (sorted; padding == 4096)
    unsigned long long m0 = __ballot(bagl[ib][j]      < PADID);
    unsigned long long m1 = __ballot(bagl[ib][32 + j] < PADID);
    const int half = ib & 1;
    const int len = __popc((unsigned)(m0 >> (half * 32)))
                  + __popc((unsigned)(m1 >> (half * 32)));

    hbuf[ib][j] = 0.f;
    asm volatile("s_waitcnt lgkmcnt(0)" ::: "memory");   // wave-local LDS fence

    float h = 0.f;
    for (int t = 0; t < MAXLEN; t++) {
        const float4* xp = (const float4*)&xbuf[ib][t][0];   // broadcast reads
        float4 x0 = xp[0], x1 = xp[1], x2 = xp[2], x3 = xp[3], x4 = xp[4];

        float s = sbias;
        const float4* hb4 = (const float4*)hbuf[ib];
#pragma unroll
        for (int m = 0; m < 8; m++) {
            float4 hv = hb4[m];
            s += whh[4*m+0]*hv.x + whh[4*m+1]*hv.y
               + whh[4*m+2]*hv.z + whh[4*m+3]*hv.w;
        }
        s += wih[0]*x0.x + wih[1]*x0.y + wih[2]*x0.z + wih[3]*x0.w;
        s += wih[4]*x1.x + wih[5]*x1.y + wih[6]*x1.z + wih[7]*x1.w;
        s += wih[8]*x2.x + wih[9]*x2.y + wih[10]*x2.z + wih[11]*x2.w;
        s += wih[12]*x3.x + wih[13]*x3.y + wih[14]*x3.z + wih[15]*x3.w;
        s += wih[16]*x4.x + wih[17]*x4.y + wih[18]*x4.z + wih[19]*x4.w;

        // fast tanh: (e^{2s}-1)/(e^{2s}+1), clamped
        s = fminf(fmaxf(s, -9.f), 9.f);
        float e = __expf(2.f * s);
        float th = (e - 1.f) * __builtin_amdgcn_rcpf(e + 1.f);

        h = (t < len) ? th : h;           // freeze past sequence length

        hbuf[ib][j] = h;
        asm volatile("s_waitcnt lgkmcnt(0)" ::: "memory");
    }

    out_h[(size_t)(gbase + ib) * HID + j] = h;
}

extern "C" void kernel_launch(void* const* d_in, const int* in_sizes, int n_in,
                              void* d_out, int out_size, void* d_ws, size_t ws_size,
                              hipStream_t stream) {
    const int*   chars     = (const int*)d_in[0];
    const int*   colors    = (const int*)d_in[1];
    const float* emb_table = (const float*)d_in[2];
    const float* W_ih      = (const float*)d_in[3];
    const float* W_hh      = (const float*)d_in[4];
    const float* b_ih      = (const float*)d_in[5];
    const float* b_hh      = (const float*)d_in[6];

    const int B = in_sizes[0] / HW;      // 8192

    float* out     = (float*)d_out;
    float* out_h   = out;                                    // [B, 32]
    float* out_emb = out + (size_t)B * HID;                  // [B, 64, 20]
    float* out_bag = out_emb + (size_t)B * MAXLEN * EMB;     // [B, 64]

    fused_kernel<<<B / SPB, 128, 0, stream>>>(chars, colors, emb_table,
                                              W_ih, W_hh, b_ih, b_hh,
                                              out_h, out_emb, out_bag);
}